// Round 10
// baseline (446.783 us; speedup 1.0000x reference)
//
#include <hip/hip_runtime.h>
#include <hip/hip_bf16.h>
#include <math.h>
#include <string.h>

// BilateralNet round 15: BARRIER-FREE wave pipelines.
// Round-14 post-mortem: conv-as-MFMA moved VALU work down (43.6->40.3 us-eq)
// but duration didn't follow (95->97). Recurring signature across r10-r14:
// pipe work moves, duration doesn't. Arithmetic: ~2000 cyc of pipe work per
// item-wave vs ~5-6x that in measured latency -> the 6 __syncthreads/item
// lockstep chain is the binding constraint (at ~2.3 resident blocks/CU there
// is nothing to fill inter-phase stalls).
// Fix: wave w owns px-column [16w,16w+16) of Xs across ALL chunks (disjoint
// -> no cross-wave hazard). Each wave computes all 64 out-ch per layer (4
// o-tile MFMAs per B-frag, B reused 4x -> LDS reads 92->30/item-wave) and
// the FULL w6 K-range (flush = 64 atomicAdds, no cross-wave reduce).
// A-frags stream as pre-converted bf16 dwordx4 from the prep-kernel ws
// (92 KB, L1/L2-hot, zero cvt VALU - fixes r13's mistake). r14's MFMA conv
// kept (already wave-local). ZERO __syncthreads in the item loop (one at
// kernel start for Ac staging).

#define NN   160
#define NPIX 25600   // 160*160

// ws layout (16B ushort8 units): dense frag(layer,s,row,lq) at
// OFF_l + (s*64+row)*4 + lq ; w6 frag(c,row16,lq) at 5120 + (c*16+row)*4+lq
#define W2OFF 0
#define W3OFF 512
#define W4OFF 1536
#define W5OFF 3072
#define W6OFF 5120
#define WSUNITS 5888   // 23 blocks x 256 threads

typedef __attribute__((ext_vector_type(4))) float float4v;
typedef __attribute__((ext_vector_type(8))) unsigned short ushort8;
typedef __attribute__((ext_vector_type(2))) unsigned int uint2v;
typedef __attribute__((ext_vector_type(4))) unsigned int uint4v;
typedef __attribute__((ext_vector_type(8))) __bf16 bf16x8;

__device__ __forceinline__ int refp(int a) { return (a <= NN - 1) ? a : (2 * (NN - 1) - a); }

__device__ __forceinline__ unsigned int pk2(float lo, float hi) {
    float2 f; f.x = lo; f.y = hi;
    __hip_bfloat162 h = __float22bfloat162_rn(f);   // v_cvt_pk_bf16_f32
    unsigned int u;
    memcpy(&u, &h, 4);
    return u;
}

// ---- prep: fp32 weights -> bf16 fragments in d_ws (frag-order layout) ----
__global__ __launch_bounds__(256) void bnet_prep_kernel(
    const float* __restrict__ w2, const float* __restrict__ w3,
    const float* __restrict__ w4, const float* __restrict__ w5,
    const float* __restrict__ w6, ushort8* __restrict__ ws)
{
    const int u = blockIdx.x * 256 + threadIdx.x;   // 0..5887
    const int lq = u & 3;
    float src[8];
    if (u < W6OFF) {
        const float* wp; int K, rel;
        if (u < W3OFF)      { wp = w2; K = 64;  rel = u; }
        else if (u < W4OFF) { wp = w3; K = 128; rel = u - W3OFF; }
        else if (u < W5OFF) { wp = w4; K = 192; rel = u - W4OFF; }
        else                { wp = w5; K = 256; rel = u - W5OFF; }
        const int arow = (rel >> 2) & 63;
        const int s = rel >> 8;
        const float* p = &wp[arow * K + s * 32 + lq * 8];
#pragma unroll
        for (int e = 0; e < 8; ++e) src[e] = p[e];
    } else {
        const int rel = u - W6OFF;        // (c*16 + r)*4 + lq, c in 0..11
        const int r = (rel >> 2) & 15;
        const int c = rel >> 6;
        if (r < 4 && c < 10) {
            const float* p = &w6[r * 320 + c * 32 + lq * 8];
#pragma unroll
            for (int e = 0; e < 8; ++e) src[e] = p[e];
        } else {
#pragma unroll
            for (int e = 0; e < 8; ++e) src[e] = 0.0f;   // pad rows/chunks
        }
    }
    uint4v o;
    o[0] = pk2(src[0], src[1]); o[1] = pk2(src[2], src[3]);
    o[2] = pk2(src[4], src[5]); o[3] = pk2(src[6], src[7]);
    ws[u] = __builtin_bit_cast(ushort8, o);
}

// one dense layer, wave-local: reads X[0..K) at own px, writes relu(W X + b)
// into X[K..K+64) at own px. All 64 out-ch computed by this wave; A-frags
// streamed from ws (L1/L2-hot), B-frag reused across the 4 o-tiles.
template <int NCH>  // K = NCH*32 input channels
__device__ __forceinline__ void dense_all(const ushort8* __restrict__ wsL,
                                          const float* __restrict__ bL,
                                          unsigned short* Xs, int px, int lo16, int lq) {
    const int K = NCH * 32;
    float4v acc[4];
#pragma unroll
    for (int ot = 0; ot < 4; ++ot) acc[ot] = *(const float4v*)&bL[ot * 16 + lq * 4];
#pragma unroll
    for (int s = 0; s < NCH; ++s) {
        const bf16x8 bf = __builtin_bit_cast(
            bf16x8, *(const ushort8*)&Xs[(s * 4 + lq) * 512 + px * 8]);
#pragma unroll
        for (int ot = 0; ot < 4; ++ot) {
            const bf16x8 af = __builtin_bit_cast(bf16x8, wsL[(s * 64 + ot * 16 + lo16) * 4 + lq]);
            acc[ot] = __builtin_amdgcn_mfma_f32_16x16x32_bf16(af, bf, acc[ot], 0, 0, 0);
        }
    }
#pragma unroll
    for (int ot = 0; ot < 4; ++ot) {
        const int cb = K + ot * 16 + lq * 4;
        uint2v o;
        o[0] = pk2(fmaxf(acc[ot][0], 0.0f), fmaxf(acc[ot][1], 0.0f));
        o[1] = pk2(fmaxf(acc[ot][2], 0.0f), fmaxf(acc[ot][3], 0.0f));
        *(uint2v*)&Xs[(cb >> 3) * 512 + px * 8 + (cb & 7)] = o;
    }
}

__global__
__attribute__((amdgpu_flat_work_group_size(256, 256)))
__attribute__((amdgpu_waves_per_eu(3, 3)))
void bnet_mlp_kernel(
    const float* __restrict__ x,
    const float* __restrict__ wx, const float* __restrict__ bx,
    const float* __restrict__ wcs, const float* __restrict__ bcs,
    const float* __restrict__ wc, const float* __restrict__ bc,
    const float* __restrict__ b2, const float* __restrict__ b3,
    const float* __restrict__ b4, const float* __restrict__ b5,
    const ushort8* __restrict__ wsb,
    float* __restrict__ par)  // par[ch][b][pix], ch-major; pre-zeroed
{
    __shared__ unsigned short Xs[20480];    // 40 chunks x (64 px x 8 ch) - px-columns wave-disjoint
    __shared__ unsigned short Ac[1536];     // conv A-frags: [3 mode][4 ot][16 row][8 k] bf16

    const int t = threadIdx.x;
    const int lane = t & 63;
    const int lo16 = lane & 15;
    const int lq = lane >> 4;
    const int w = __builtin_amdgcn_readfirstlane(t >> 6);  // wave id 0..3 = px-tile
    const int px = w * 16 + lo16;                          // own pixel column in Xs

    // ---- stage conv A-frags into LDS once per block: taps 0..3, rest zero ----
    if (t < 192) {
        const int m = t >> 6, ch = t & 63;
        const float* w1m = (m == 0) ? wx : (m == 1) ? wcs : wc;
        const float4v wv = *(const float4v*)&w1m[ch * 4];
        uint4v o;
        o[0] = pk2(wv[0], wv[1]); o[1] = pk2(wv[2], wv[3]);
        o[2] = 0u; o[3] = 0u;
        *(uint4v*)&Ac[((m * 4 + (ch >> 4)) * 16 + (ch & 15)) * 8] = o;
    }
    __syncthreads();   // the ONLY block-wide barrier (Ac init)

    // ---- item chunk: 9600 items over 768 blocks -> 384 x13 + 384 x12 ----
    const int bid = blockIdx.x;
    const int nit = 12 + (bid < 384 ? 1 : 0);
    const int g0  = (bid < 384) ? bid * 13 : bid * 12 + 384;

    // w6 accumulator: full K per wave; rows 0..3 (lq==0 lanes) are the 4 pars
    // for own 16 px. Persists across the 12 (mode,rot) variants of a tb.
    float4v acc6 = {0.f, 0.f, 0.f, 0.f};
    int cur_tb = -1;

    for (int it = 0; it < nit; ++it) {
        const int g = g0 + it;            // g = (tile*2+b)*12 + (mode*4+k)
        const int v = g % 12;
        const int tb = g / 12;
        const int tile = tb >> 1;
        const int b = tb & 1;
        const int mode = v >> 2;          // 0='x', 1='s', 2='c'
        const int k = v & 3;              // rotation

        if (tb != cur_tb) {               // block-uniform condition
            if (cur_tb >= 0) {
                // flush prev tb: wave-local, no reduce, no barrier
                const int ftile = cur_tb >> 1;
                const int fb = cur_tb & 1;
                if (lq == 0) {
                    const int pixg = ftile * 64 + px;
#pragma unroll
                    for (int r = 0; r < 4; ++r)
                        atomicAdd(&par[(r * 2 + fb) * NPIX + pixg], acc6[r]);  // b6 folded into kernel 2
                }
                float4v z = {0.f, 0.f, 0.f, 0.f}; acc6 = z;
            }
            cur_tb = tb;
        }

        const float* xb = x + b * NPIX;
        const float* b1 = (mode == 0) ? bx : (mode == 1) ? bcs : bc;

        // ---- stage 1 conv via MFMA: thread (w,lq,lo16) gathers ONE tap ----
        // tap index = lq; pixel = tile*64 + px (wave w owns px-tile w)
        int dy, dx;
        if (mode == 0)      { dy = lq >> 1;        dx = lq & 1; }
        else if (mode == 1) { dy = (lq == 0) ? 0 : (lq == 3) ? 2 : 1;
                              dx = (lq == 0) ? 0 : (lq == 2) ? 2 : 1; }
        else                { dy = (lq >> 1) * 2;  dx = (lq & 1) * 2; }

        const int gpix = tile * 64 + px;
        const int gpi = gpix / NN;
        const int gpj = gpix - gpi * NN;
        int rr, cc;
        if (k == 0)      { rr = refp(gpi + dy); cc = refp(gpj + dx); }
        else if (k == 1) { rr = refp(gpi + dx); cc = (gpj >= dy) ? (gpj - dy) : (dy - gpj); }
        else if (k == 2) { rr = (gpi >= dy) ? (gpi - dy) : (dy - gpi);
                           cc = (gpj >= dx) ? (gpj - dx) : (dx - gpj); }
        else             { rr = (gpi >= dx) ? (gpi - dx) : (dx - gpi); cc = refp(gpj + dy); }
        const float gval = xb[rr * NN + cc];

        // B-frag: lane needs taps 0..3 of pixel (w,lo16); tap e lives in lane e*16+lo16
        const float tv0 = __shfl(gval, 0 * 16 + lo16);
        const float tv1 = __shfl(gval, 1 * 16 + lo16);
        const float tv2 = __shfl(gval, 2 * 16 + lo16);
        const float tv3 = __shfl(gval, 3 * 16 + lo16);
        uint4v bu;
        bu[0] = pk2(tv0, tv1); bu[1] = pk2(tv2, tv3); bu[2] = 0u; bu[3] = 0u;
        if (lq != 0) { bu[0] = 0u; bu[1] = 0u; }     // k>=8 lanes all zero
        const bf16x8 bfrag = __builtin_bit_cast(bf16x8, bu);

#pragma unroll
        for (int ot = 0; ot < 4; ++ot) {
            uint4v au = *(const uint4v*)&Ac[((mode * 4 + ot) * 16 + lo16) * 8];
            if (lq != 0) { au[0] = 0u; au[1] = 0u; au[2] = 0u; au[3] = 0u; }
            const bf16x8 afrag = __builtin_bit_cast(bf16x8, au);
            float4v acc = *(const float4v*)&b1[ot * 16 + lq * 4];   // bias init
            acc = __builtin_amdgcn_mfma_f32_16x16x32_bf16(afrag, bfrag, acc, 0, 0, 0);
            const int cb = ot * 16 + lq * 4;
            uint2v o;
            o[0] = pk2(fmaxf(acc[0], 0.0f), fmaxf(acc[1], 0.0f));
            o[1] = pk2(fmaxf(acc[2], 0.0f), fmaxf(acc[3], 0.0f));
            *(uint2v*)&Xs[(cb >> 3) * 512 + px * 8 + (cb & 7)] = o;
        }
        // no barrier: this wave's LDS ops are in-order; px-columns disjoint

        dense_all<2>(wsb + W2OFF, b2, Xs, px, lo16, lq);
        dense_all<4>(wsb + W3OFF, b3, Xs, px, lo16, lq);
        dense_all<6>(wsb + W4OFF, b4, Xs, px, lo16, lq);
        dense_all<8>(wsb + W5OFF, b5, Xs, px, lo16, lq);

        // ---- final layer: full 10 K-chunks, own px ----
#pragma unroll
        for (int c = 0; c < 10; ++c) {
            const bf16x8 bf = __builtin_bit_cast(
                bf16x8, *(const ushort8*)&Xs[(c * 4 + lq) * 512 + px * 8]);
            const bf16x8 af = __builtin_bit_cast(bf16x8, wsb[W6OFF + (c * 16 + lo16) * 4 + lq]);
            acc6 = __builtin_amdgcn_mfma_f32_16x16x32_bf16(af, bf, acc6, 0, 0, 0);
        }
    }

    // ---- final flush of the last tb ----
    {
        const int ftile = cur_tb >> 1;
        const int fb = cur_tb & 1;
        if (lq == 0) {
            const int pixg = ftile * 64 + px;
#pragma unroll
            for (int r = 0; r < 4; ++r)
                atomicAdd(&par[(r * 2 + fb) * NPIX + pixg], acc6[r]);  // b6 folded into kernel 2
        }
    }
}

__global__ __launch_bounds__(64) void bnet_bilateral_kernel(
    const float* __restrict__ x, const float* __restrict__ b6,
    float* __restrict__ out)
{
    const int tid = blockIdx.x * 64 + threadIdx.x;  // 800 blocks x 64 = 51200 exactly
    const int b = tid / NPIX;
    const int pix = tid - b * NPIX;
    const int pi = pix / NN;
    const int pj = pix - pi * NN;

    float* par = out + 2 * NPIX;
    const float inv12 = 1.0f / 12.0f;
    const float p0 = par[(0 + b) * NPIX + pix] * inv12 + b6[0];
    const float p1 = par[(2 + b) * NPIX + pix] * inv12 + b6[1];
    const float p2 = par[(4 + b) * NPIX + pix] * inv12 + b6[2];
    const float p3 = par[(6 + b) * NPIX + pix] * inv12 + b6[3];

    float sigx = 1.0f / (1.0f + __expf(-p0)) + 1e-6f;
    sigx = fminf(fmaxf(sigx, 0.0f), 1.0f);
    float sigy = 1.0f / (1.0f + __expf(-p1)) + 1e-6f;
    sigy = fminf(fmaxf(sigy, 0.0f), 1.0f);
    float t2 = __expf(2.0f * fminf(fmaxf(p2, -15.0f), 15.0f));
    float th = (t2 - 1.0f) / (t2 + 1.0f);
    th = fminf(fmaxf(th, -1.0f), 1.0f);
    float t3 = __expf(2.0f * fminf(fmaxf(p3, -15.0f), 15.0f));
    float sigr = (t3 - 1.0f) / (t3 + 1.0f) + 1e-6f;
    sigr = fminf(fmaxf(sigr, -1.0f), 1.0f);

    par[(0 + b) * NPIX + pix] = sigx;
    par[(2 + b) * NPIX + pix] = sigy;
    par[(4 + b) * NPIX + pix] = th;
    par[(6 + b) * NPIX + pix] = sigr;

    const float sx = sigx * 20.0f;
    const float sy = sigy * 20.0f;
    const float sr = sigr * 10.0f + 10.0f;

    const float* xb = x + b * NPIX;
    float patch[5][5];
#pragma unroll
    for (int ky = 0; ky < 5; ++ky) {
#pragma unroll
        for (int kx = 0; kx < 5; ++kx) {
            const int r = pi + ky - 2, c = pj + kx - 2;
            patch[ky][kx] = (r >= 0 && r < NN && c >= 0 && c < NN) ? xb[r * NN + c] : 0.0f;
        }
    }

    const float inv2sr2 = 1.0f / (2.0f * sr * sr);
    float num = 0.0f, den = 0.0f;
#pragma unroll
    for (int ky = 0; ky < 5; ++ky) {
#pragma unroll
        for (int kx = 0; kx < 5; ++kx) {
            const float v = patch[ky][kx];
            const float dxv = fabsf(patch[2][kx] - v);
            const float dyv = fabsf(patch[ky][2] - v);
            const float a = sx * dxv;
            const float bb = sy * dyv;
            const float sq = (float)((ky - 2) * (ky - 2) + (kx - 2) * (kx - 2));
            const float kern = __expf(-sq * inv2sr2 - 0.5f * (a * a - 2.0f * th * a * bb + bb * bb));
            den += kern;
            num = fmaf(kern, v, num);
        }
    }
    out[tid] = num / den;
}

extern "C" void kernel_launch(void* const* d_in, const int* in_sizes, int n_in,
                              void* d_out, int out_size, void* d_ws, size_t ws_size,
                              hipStream_t stream) {
    const float* x   = (const float*)d_in[0];
    const float* wx  = (const float*)d_in[1];
    const float* bx  = (const float*)d_in[2];
    const float* wc  = (const float*)d_in[3];
    const float* bc  = (const float*)d_in[4];
    const float* wcs = (const float*)d_in[5];
    const float* bcs = (const float*)d_in[6];
    const float* w2  = (const float*)d_in[7];
    const float* b2  = (const float*)d_in[8];
    const float* w3  = (const float*)d_in[9];
    const float* b3  = (const float*)d_in[10];
    const float* w4  = (const float*)d_in[11];
    const float* b4  = (const float*)d_in[12];
    const float* w5  = (const float*)d_in[13];
    const float* b5  = (const float*)d_in[14];
    const float* w6  = (const float*)d_in[15];
    const float* b6  = (const float*)d_in[16];
    float* out = (float*)d_out;
    ushort8* ws = (ushort8*)d_ws;

    // zero the par accumulator region (d_out tail, re-poisoned each launch)
    (void)hipMemsetAsync(out + 2 * NPIX, 0, 8 * NPIX * sizeof(float), stream);

    // convert weights fp32 -> bf16 fragments into workspace (cache-resident)
    hipLaunchKernelGGL(bnet_prep_kernel, dim3(WSUNITS / 256), dim3(256), 0, stream,
                       w2, w3, w4, w5, w6, ws);

    hipLaunchKernelGGL(bnet_mlp_kernel, dim3(768), dim3(256), 0, stream,
                       x, wx, bx, wcs, bcs, wc, bc,
                       b2, b3, b4, b5, (const ushort8*)ws,
                       out + 2 * NPIX);

    hipLaunchKernelGGL(bnet_bilateral_kernel, dim3(800), dim3(64), 0, stream,
                       x, b6, out);
}

// Round 11
// 169.575 us; speedup vs baseline: 2.6347x; 2.6347x over previous
//
#include <hip/hip_runtime.h>
#include <hip/hip_bf16.h>
#include <math.h>
#include <string.h>

// BilateralNet round 16: clustered B-fragment loads (ILP / latency-chain attack).
// Round-15 post-mortem: wave-local + global A-streaming exploded FETCH to
// 347 MB (each frag load = 64 lanes x 16B = 1KB/wave; 90/item-wave thrashed
// L2) -> MfmaUtil 6.5%. Confounded test; reverted.
// Falsified so far on the r9 base (94.9us mlp): LDS throughput (r10), VALU
// work (r14), occupancy knobs (r9/r13), launch count (r12), weight residency
// (r8/r11/r15). Remaining suspect consistent with ALL data: per-MFMA ds_read
// latency chains under register starvation (VGPR=84, ~92 reads/item-wave x
// ~120cyc exposed, ~2.3 waves/SIMD coverage ~= the observed ~6000cyc/item
// latency vs ~2000cyc pipe work).
// Fix (r9 verbatim otherwise): dense_layer + w6 phase load B-frags in
// batches of 4 s-chunks (8 clustered ds_read_b128 -> named register arrays,
// static indices) BEFORE the MFMA chain. Same accumulation order ->
// bit-identical numerics.

#define NN   160
#define NPIX 25600   // 160*160

typedef __attribute__((ext_vector_type(4))) float float4v;
typedef __attribute__((ext_vector_type(8))) unsigned short ushort8;
typedef __attribute__((ext_vector_type(2))) unsigned int uint2v;
typedef __attribute__((ext_vector_type(4))) unsigned int uint4v;
typedef __attribute__((ext_vector_type(8))) __bf16 bf16x8;

// opaque read-write: forces one-time materialization of the converted value
#define PINV(x) asm volatile("" : "+v"(x))

__device__ __forceinline__ int refp(int a) { return (a <= NN - 1) ? a : (2 * (NN - 1) - a); }

__device__ __forceinline__ unsigned int pk2(float lo, float hi) {
    float2 f; f.x = lo; f.y = hi;
    __hip_bfloat162 h = __float22bfloat162_rn(f);   // v_cvt_pk_bf16_f32
    unsigned int u;
    memcpy(&u, &h, 4);
    return u;
}
__device__ __forceinline__ ushort8 cvt8(const float* __restrict__ p) {
    const float4v f0 = *(const float4v*)p;
    const float4v f1 = *(const float4v*)(p + 4);
    uint4v u;
    u[0] = pk2(f0[0], f0[1]); u[1] = pk2(f0[2], f0[3]);
    u[2] = pk2(f1[0], f1[1]); u[3] = pk2(f1[2], f1[3]);
    return __builtin_bit_cast(ushort8, u);
}

// one dense layer: reads X[0..K), writes relu(W X + b) into X[K..K+64).
// B-fragments are loaded in clustered batches of up to 4 s-chunks (8
// ds_read_b128 back-to-back) into named register arrays, THEN the MFMA
// chain runs — breaks the read->MFMA latency serialization.
template <int NCH>  // K = NCH*32 input channels
__device__ __forceinline__ void dense_layer(const ushort8 (&A)[NCH], float4v biasv,
                                            unsigned short* Xs, int w, int lo16, int lq) {
    const int K = NCH * 32;
#pragma unroll
    for (int pp = 0; pp < 2; ++pp) {
        const int px0 = (pp * 2) * 16 + lo16;
        const int px1 = (pp * 2 + 1) * 16 + lo16;
        float4v acc0 = biasv, acc1 = biasv;
#pragma unroll
        for (int sb = 0; sb < NCH; sb += 4) {
            const int SB = (NCH - sb < 4) ? (NCH - sb) : 4;
            ushort8 bf0[4], bf1[4];
#pragma unroll
            for (int u = 0; u < SB; ++u) {
                const int c8 = (sb + u) * 4 + lq;
                bf0[u] = *(const ushort8*)&Xs[c8 * 512 + px0 * 8];
                bf1[u] = *(const ushort8*)&Xs[c8 * 512 + px1 * 8];
            }
#pragma unroll
            for (int u = 0; u < SB; ++u) {
                acc0 = __builtin_amdgcn_mfma_f32_16x16x32_bf16(
                    __builtin_bit_cast(bf16x8, A[sb + u]),
                    __builtin_bit_cast(bf16x8, bf0[u]), acc0, 0, 0, 0);
                acc1 = __builtin_amdgcn_mfma_f32_16x16x32_bf16(
                    __builtin_bit_cast(bf16x8, A[sb + u]),
                    __builtin_bit_cast(bf16x8, bf1[u]), acc1, 0, 0, 0);
            }
        }
        const int cb = K + w * 16 + lq * 4;
        uint2v o0, o1;
        o0[0] = pk2(fmaxf(acc0[0], 0.0f), fmaxf(acc0[1], 0.0f));
        o0[1] = pk2(fmaxf(acc0[2], 0.0f), fmaxf(acc0[3], 0.0f));
        o1[0] = pk2(fmaxf(acc1[0], 0.0f), fmaxf(acc1[1], 0.0f));
        o1[1] = pk2(fmaxf(acc1[2], 0.0f), fmaxf(acc1[3], 0.0f));
        *(uint2v*)&Xs[(cb >> 3) * 512 + px0 * 8 + (cb & 7)] = o0;
        *(uint2v*)&Xs[(cb >> 3) * 512 + px1 * 8 + (cb & 7)] = o1;
    }
    __syncthreads();
}

__global__
__attribute__((amdgpu_flat_work_group_size(256, 256)))
__attribute__((amdgpu_waves_per_eu(3, 3)))
void bnet_mlp_kernel(
    const float* __restrict__ x,
    const float* __restrict__ wx, const float* __restrict__ bx,
    const float* __restrict__ wcs, const float* __restrict__ bcs,
    const float* __restrict__ wc, const float* __restrict__ bc,
    const float* __restrict__ w2, const float* __restrict__ b2,
    const float* __restrict__ w3, const float* __restrict__ b3,
    const float* __restrict__ w4, const float* __restrict__ b4,
    const float* __restrict__ w5, const float* __restrict__ b5,
    const float* __restrict__ w6,
    float* __restrict__ par)  // par[ch][b][pix], ch-major; pre-zeroed
{
    __shared__ unsigned short Xs[20480];    // 40 chunks x 1024 B = 40 KB exactly
    float* red = (float*)Xs;                // 4 KB aliased into chunks 0-3 (dead at flush)

    const int t = threadIdx.x;
    const int lane = t & 63;
    const int lo16 = lane & 15;
    const int lq = lane >> 4;
    const int w = __builtin_amdgcn_readfirstlane(t >> 6);  // wave id 0..3 = o-tile

    // ---- stage this wave's A-fragments ONCE per block (fp32 -> bf16 inline) ----
    const int arow = w * 16 + lo16;
    ushort8 a2[2], a3[4], a4[6], a5[8], a6[3];
#pragma unroll
    for (int s = 0; s < 2; ++s) { a2[s] = cvt8(&w2[arow * 64 + s * 32 + lq * 8]);  PINV(a2[s]); }
#pragma unroll
    for (int s = 0; s < 4; ++s) { a3[s] = cvt8(&w3[arow * 128 + s * 32 + lq * 8]); PINV(a3[s]); }
#pragma unroll
    for (int s = 0; s < 6; ++s) { a4[s] = cvt8(&w4[arow * 192 + s * 32 + lq * 8]); PINV(a4[s]); }
#pragma unroll
    for (int s = 0; s < 8; ++s) { a5[s] = cvt8(&w5[arow * 256 + s * 32 + lq * 8]); PINV(a5[s]); }
#pragma unroll
    for (int c = 0; c < 3; ++c) {
        // w6 is 4x320; padded to 16 rows. wave w covers K-chunks 3w..3w+2.
        const int ch = (3 * w + c) * 32;
        if (ch < 320 && lo16 < 4) {
            a6[c] = cvt8(&w6[lo16 * 320 + ch + lq * 8]);
        } else {
            ushort8 z = {0, 0, 0, 0, 0, 0, 0, 0};
            a6[c] = z;
        }
        PINV(a6[c]);
    }
    const float4v b2v = *(const float4v*)&b2[w * 16 + lq * 4];
    const float4v b3v = *(const float4v*)&b3[w * 16 + lq * 4];
    const float4v b4v = *(const float4v*)&b4[w * 16 + lq * 4];
    const float4v b5v = *(const float4v*)&b5[w * 16 + lq * 4];

    // ---- item chunk: 9600 items over 768 blocks -> 384 x13 + 384 x12 ----
    const int bid = blockIdx.x;
    const int nit = 12 + (bid < 384 ? 1 : 0);
    const int g0  = (bid < 384) ? bid * 13 : bid * 12 + 384;

    // w6 partial accumulator: persists across all variants of the same (tile,b)
    float4v acc6[4];
    int cur_tb = -1;

    for (int it = 0; it < nit; ++it) {
        const int g = g0 + it;            // g = (tile*2+b)*12 + (mode*4+k)
        const int v = g % 12;
        const int tb = g / 12;
        const int tile = tb >> 1;
        const int b = tb & 1;
        const int mode = v >> 2;          // 0='x', 1='s', 2='c'
        const int k = v & 3;              // rotation

        __syncthreads();  // prior item's w6 reads of Xs done; Xs/red reusable

        if (tb != cur_tb) {               // block-uniform condition
            if (cur_tb >= 0) {
                // ---- flush prev tb: reduce partials across waves, 1 atomic set ----
                const int ftile = cur_tb >> 1;
                const int fb = cur_tb & 1;
                if (lq == 0) {
#pragma unroll
                    for (int pt = 0; pt < 4; ++pt)
                        *(float4v*)&red[(((w * 4) + pt) * 16 + lo16) * 4] = acc6[pt];
                }
                __syncthreads();
                if (w == 0) {
                    float4v sv;
#pragma unroll
                    for (int r = 0; r < 4; ++r)
                        sv[r] = red[(((0 * 4) + lq) * 16 + lo16) * 4 + r]
                              + red[(((1 * 4) + lq) * 16 + lo16) * 4 + r]
                              + red[(((2 * 4) + lq) * 16 + lo16) * 4 + r]
                              + red[(((3 * 4) + lq) * 16 + lo16) * 4 + r];
                    const int pixg = ftile * 64 + lq * 16 + lo16;
#pragma unroll
                    for (int r = 0; r < 4; ++r)
                        atomicAdd(&par[(r * 2 + fb) * NPIX + pixg], sv[r]);  // b6 folded into kernel 2
                }
                __syncthreads();  // wave 0 done with red before conv overwrites chunks 0-3
            }
#pragma unroll
            for (int pt = 0; pt < 4; ++pt) { float4v z = {0.f, 0.f, 0.f, 0.f}; acc6[pt] = z; }
            cur_tb = tb;
        }

        const float* xb = x + b * NPIX;
        const float* w1 = (mode == 0) ? wx : (mode == 1) ? wcs : wc;
        const float* b1 = (mode == 0) ? bx : (mode == 1) ? bcs : bc;
        int DY[4], DX[4];
        if (mode == 0)      { DY[0]=0; DY[1]=0; DY[2]=1; DY[3]=1;  DX[0]=0; DX[1]=1; DX[2]=0; DX[3]=1; }
        else if (mode == 1) { DY[0]=0; DY[1]=1; DY[2]=1; DY[3]=2;  DX[0]=0; DX[1]=1; DX[2]=2; DX[3]=1; }
        else                { DY[0]=0; DY[1]=0; DY[2]=2; DY[3]=2;  DX[0]=0; DX[1]=2; DX[2]=0; DX[3]=2; }

        const int pix = tile * 64 + lane;
        const int pi = pix / NN;
        const int pj = pix - pi * NN;

        // ---- stage 1: 4-tap conv; thread owns ch w*16..+15 at px=lane ----
        float s4[4];
#pragma unroll
        for (int tt = 0; tt < 4; ++tt) {
            const int dy = DY[tt], dx = DX[tt];
            int r, c;
            if (k == 0)      { r = refp(pi + dy); c = refp(pj + dx); }
            else if (k == 1) { r = refp(pi + dx); c = (pj >= dy) ? (pj - dy) : (dy - pj); }
            else if (k == 2) { r = (pi >= dy) ? (pi - dy) : (dy - pi);
                               c = (pj >= dx) ? (pj - dx) : (dx - pj); }
            else             { r = (pi >= dx) ? (pi - dx) : (dx - pi); c = refp(pj + dy); }
            s4[tt] = xb[r * NN + c];
        }
        float4v b1v[4];
#pragma unroll
        for (int q = 0; q < 4; ++q) b1v[q] = *(const float4v*)&b1[w * 16 + q * 4];
        float co[16];
#pragma unroll
        for (int oo = 0; oo < 16; ++oo) {
            const int o = w * 16 + oo;
            const float4v wv = *(const float4v*)&w1[o * 4];
            float cacc = b1v[oo >> 2][oo & 3];
#pragma unroll
            for (int tt = 0; tt < 4; ++tt) cacc = fmaf(wv[tt], s4[tt], cacc);
            co[oo] = fmaxf(cacc, 0.0f);
        }
        uint4v pka, pkb;
#pragma unroll
        for (int q = 0; q < 4; ++q) {
            pka[q] = pk2(co[2 * q], co[2 * q + 1]);
            pkb[q] = pk2(co[8 + 2 * q], co[9 + 2 * q]);
        }
        *(uint4v*)&Xs[(w * 2) * 512 + lane * 8]     = pka;
        *(uint4v*)&Xs[(w * 2 + 1) * 512 + lane * 8] = pkb;
        __syncthreads();

        dense_layer<2>(a2, b2v, Xs, w, lo16, lq);
        dense_layer<4>(a3, b3v, Xs, w, lo16, lq);
        dense_layer<6>(a4, b4v, Xs, w, lo16, lq);
        dense_layer<8>(a5, b5v, Xs, w, lo16, lq);

        // ---- final layer partials: wave w covers K-chunks 3w..3w+2 ----
        // batch the 3 B-frag reads per pt before the MFMA chain
#pragma unroll
        for (int pt = 0; pt < 4; ++pt) {
            const int px = pt * 16 + lo16;
            ushort8 bfa[3];
#pragma unroll
            for (int c = 0; c < 3; ++c) {
                int chb = (3 * w + c) * 32;
                chb = (chb < 288) ? chb : 288;   // clamp: A is zero there anyway
                const int c8 = (chb >> 3) + lq;
                bfa[c] = *(const ushort8*)&Xs[c8 * 512 + px * 8];
            }
#pragma unroll
            for (int c = 0; c < 3; ++c) {
                acc6[pt] = __builtin_amdgcn_mfma_f32_16x16x32_bf16(
                    __builtin_bit_cast(bf16x8, a6[c]),
                    __builtin_bit_cast(bf16x8, bfa[c]), acc6[pt], 0, 0, 0);
            }
        }
        // loop-top __syncthreads() protects Xs reuse across items
    }

    // ---- final flush of the last tb ----
    __syncthreads();   // all w6 reads of Xs complete before red aliases it
    {
        const int ftile = cur_tb >> 1;
        const int fb = cur_tb & 1;
        if (lq == 0) {
#pragma unroll
            for (int pt = 0; pt < 4; ++pt)
                *(float4v*)&red[(((w * 4) + pt) * 16 + lo16) * 4] = acc6[pt];
        }
        __syncthreads();
        if (w == 0) {
            float4v sv;
#pragma unroll
            for (int r = 0; r < 4; ++r)
                sv[r] = red[(((0 * 4) + lq) * 16 + lo16) * 4 + r]
                      + red[(((1 * 4) + lq) * 16 + lo16) * 4 + r]
                      + red[(((2 * 4) + lq) * 16 + lo16) * 4 + r]
                      + red[(((3 * 4) + lq) * 16 + lo16) * 4 + r];
            const int pixg = ftile * 64 + lq * 16 + lo16;
#pragma unroll
            for (int r = 0; r < 4; ++r)
                atomicAdd(&par[(r * 2 + fb) * NPIX + pixg], sv[r]);  // b6 folded into kernel 2
        }
    }
}

__global__ __launch_bounds__(64) void bnet_bilateral_kernel(
    const float* __restrict__ x, const float* __restrict__ b6,
    float* __restrict__ out)
{
    const int tid = blockIdx.x * 64 + threadIdx.x;  // 800 blocks x 64 = 51200 exactly
    const int b = tid / NPIX;
    const int pix = tid - b * NPIX;
    const int pi = pix / NN;
    const int pj = pix - pi * NN;

    float* par = out + 2 * NPIX;
    const float inv12 = 1.0f / 12.0f;
    const float p0 = par[(0 + b) * NPIX + pix] * inv12 + b6[0];
    const float p1 = par[(2 + b) * NPIX + pix] * inv12 + b6[1];
    const float p2 = par[(4 + b) * NPIX + pix] * inv12 + b6[2];
    const float p3 = par[(6 + b) * NPIX + pix] * inv12 + b6[3];

    float sigx = 1.0f / (1.0f + __expf(-p0)) + 1e-6f;
    sigx = fminf(fmaxf(sigx, 0.0f), 1.0f);
    float sigy = 1.0f / (1.0f + __expf(-p1)) + 1e-6f;
    sigy = fminf(fmaxf(sigy, 0.0f), 1.0f);
    float t2 = __expf(2.0f * fminf(fmaxf(p2, -15.0f), 15.0f));
    float th = (t2 - 1.0f) / (t2 + 1.0f);
    th = fminf(fmaxf(th, -1.0f), 1.0f);
    float t3 = __expf(2.0f * fminf(fmaxf(p3, -15.0f), 15.0f));
    float sigr = (t3 - 1.0f) / (t3 + 1.0f) + 1e-6f;
    sigr = fminf(fmaxf(sigr, -1.0f), 1.0f);

    par[(0 + b) * NPIX + pix] = sigx;
    par[(2 + b) * NPIX + pix] = sigy;
    par[(4 + b) * NPIX + pix] = th;
    par[(6 + b) * NPIX + pix] = sigr;

    const float sx = sigx * 20.0f;
    const float sy = sigy * 20.0f;
    const float sr = sigr * 10.0f + 10.0f;

    const float* xb = x + b * NPIX;
    float patch[5][5];
#pragma unroll
    for (int ky = 0; ky < 5; ++ky) {
#pragma unroll
        for (int kx = 0; kx < 5; ++kx) {
            const int r = pi + ky - 2, c = pj + kx - 2;
            patch[ky][kx] = (r >= 0 && r < NN && c >= 0 && c < NN) ? xb[r * NN + c] : 0.0f;
        }
    }

    const float inv2sr2 = 1.0f / (2.0f * sr * sr);
    float num = 0.0f, den = 0.0f;
#pragma unroll
    for (int ky = 0; ky < 5; ++ky) {
#pragma unroll
        for (int kx = 0; kx < 5; ++kx) {
            const float v = patch[ky][kx];
            const float dxv = fabsf(patch[2][kx] - v);
            const float dyv = fabsf(patch[ky][2] - v);
            const float a = sx * dxv;
            const float bb = sy * dyv;
            const float sq = (float)((ky - 2) * (ky - 2) + (kx - 2) * (kx - 2));
            const float kern = __expf(-sq * inv2sr2 - 0.5f * (a * a - 2.0f * th * a * bb + bb * bb));
            den += kern;
            num = fmaf(kern, v, num);
        }
    }
    out[tid] = num / den;
}

extern "C" void kernel_launch(void* const* d_in, const int* in_sizes, int n_in,
                              void* d_out, int out_size, void* d_ws, size_t ws_size,
                              hipStream_t stream) {
    const float* x   = (const float*)d_in[0];
    const float* wx  = (const float*)d_in[1];
    const float* bx  = (const float*)d_in[2];
    const float* wc  = (const float*)d_in[3];
    const float* bc  = (const float*)d_in[4];
    const float* wcs = (const float*)d_in[5];
    const float* bcs = (const float*)d_in[6];
    const float* w2  = (const float*)d_in[7];
    const float* b2  = (const float*)d_in[8];
    const float* w3  = (const float*)d_in[9];
    const float* b3  = (const float*)d_in[10];
    const float* w4  = (const float*)d_in[11];
    const float* b4  = (const float*)d_in[12];
    const float* w5  = (const float*)d_in[13];
    const float* b5  = (const float*)d_in[14];
    const float* w6  = (const float*)d_in[15];
    const float* b6  = (const float*)d_in[16];
    float* out = (float*)d_out;

    // zero the par accumulator region (d_out tail, re-poisoned each launch)
    (void)hipMemsetAsync(out + 2 * NPIX, 0, 8 * NPIX * sizeof(float), stream);

    hipLaunchKernelGGL(bnet_mlp_kernel, dim3(768), dim3(256), 0, stream,
                       x, wx, bx, wcs, bcs, wc, bc,
                       w2, b2, w3, b3, w4, b4, w5, b5, w6,
                       out + 2 * NPIX);

    hipLaunchKernelGGL(bnet_bilateral_kernel, dim3(800), dim3(64), 0, stream,
                       x, b6, out);
}